// Round 2
// 149.035 us; speedup vs baseline: 1.0991x; 1.0991x over previous
//
#include <hip/hip_runtime.h>
#include <math.h>

// TemporalSNNClassifier — bit-exact fp32 emulation (absmax 0.0 since r2).
//
// r16b: tloop phase-B unpack elimination via v_fma_mix_f32. Spikes are
// exactly {0.0f, 1.0f} = fp16-exact, so pack them as fp16 pairs
// (v_cvt_pkrtz_f16_f32: 1 inst per pair, exact for 0/1) and let
// v_fma_mix_f32 op_sel pick the half and convert fp16->fp32 (exact) inside
// a single full-rate fp32 FMA with ONE rounding — bit-identical to the
// frozen fmaf(spk,w,acc) h-ascending chain, but 1 inst instead of
// unpack+fma (2 insts). Cuts tloop VALU insts/thread ~23k -> ~14.7k.
// LDS layout/traffic unchanged. gemm (kernel A) untouched this round.
// (r16 fix: cvt_pkrtz returns __fp16 ext-vector; use auto + bit_cast.)
//
// r15 evidence: tloop 83us @ VALU 84.8%; gemm invariant at ~81us across 4
// implementations. Unified law (r10+r12+m136): 16B-per-lane reads are NEVER
// deduplicated — a wave-uniform b128 (global OR LDS) moves 64x16B and
// serializes on the bank quad (~64cyc). x staged as 4x ds_read_b32
// broadcasts (m136: b32 same-address broadcast is FREE), c-major stride-33.
//
// FROZEN numerics: k-ascending single-accumulator fmaf chains (GEMM1),
// h-ascending 0..127 chain per (row,class,t) over spike 1.0f/+0.0f
// (fma(s,w,a), s in {0,1}, acc never -0: bit-exact), bias as one separate
// add, leaky update ((0.9f*mem)+cur)-reset with contraction off,
// spike <=> mem > 1.0f, reset_t == spk_{t-1}.

#define T_STEPS 64
#define IN_DIM  256
#define HID     128
#define NCLS    8

// ---------------- kernel A: cur1 GEMM -> ws (r15 verbatim) ----------------
#define A_THR  256
#define A_ROWS 32
#define A_KQ   16     // float4 k-quads per chunk (64 k)

__global__ __launch_bounds__(A_THR, 2)
void snn_gemm(const float* __restrict__ x, const float* __restrict__ W1,
              const float* __restrict__ b1, float* __restrict__ ws)
{
#pragma clang fp contract(off)
    __shared__ float4 w1c[A_KQ][HID + 2];   // 33.3 KB, lane-contig reads
    __shared__ float  xcf[64 * 33];         // 8.4 KB, c-major stride 33

    const int tid  = threadIdx.x;
    const int lane = tid & 63;
    const int wv   = __builtin_amdgcn_readfirstlane(tid >> 6);   // 0..3
    const size_t rowg0 = (size_t)blockIdx.x * A_ROWS;

    float accL[8], accH[8];
    #pragma unroll
    for (int j = 0; j < 8; ++j) { accL[j] = 0.0f; accH[j] = 0.0f; }

    #pragma unroll 1
    for (int ch = 0; ch < 4; ++ch) {
        const int kbase = ch * (A_KQ * 4);
        // stage W1 chunk: 2048 float4, 8 per thread (coalesced per h-row)
        #pragma unroll
        for (int s = 0; s < 8; ++s) {
            const int idx = tid + s * A_THR;
            const int h = idx >> 4, kq = idx & 15;
            w1c[kq][h] = *(const float4*)(W1 + (size_t)h * IN_DIM + kbase + kq * 4);
        }
        // stage x chunk c-major: quad (rr,kq) -> xcf[(4kq+c)*33 + rr]
        // write banks (4kq+c+rr) mod 32 -> 2-way max (free)
        #pragma unroll
        for (int s = 0; s < 2; ++s) {
            const int idx = tid + s * A_THR;
            const int rr = idx >> 4, kq = idx & 15;
            const float4 v = *(const float4*)(x + (rowg0 + rr) * IN_DIM + kbase + kq * 4);
            xcf[(4 * kq + 0) * 33 + rr] = v.x;
            xcf[(4 * kq + 1) * 33 + rr] = v.y;
            xcf[(4 * kq + 2) * 33 + rr] = v.z;
            xcf[(4 * kq + 3) * 33 + rr] = v.w;
        }
        __syncthreads();

        #pragma unroll 4
        for (int kq = 0; kq < A_KQ; ++kq) {
            const float4 wL = w1c[kq][lane];        // lane-contig 1KB, 8cyc
            const float4 wH = w1c[kq][64 + lane];
            #pragma unroll
            for (int j = 0; j < 8; ++j) {
                const int rb = wv * 8 + j;
                // 4 separate b32 broadcasts (132B apart -> no b128 merge)
                const float x0 = xcf[(4 * kq + 0) * 33 + rb];
                const float x1 = xcf[(4 * kq + 1) * 33 + rb];
                const float x2 = xcf[(4 * kq + 2) * 33 + rb];
                const float x3 = xcf[(4 * kq + 3) * 33 + rb];
                float aL = accL[j], aH = accH[j];
                aL = fmaf(x0, wL.x, aL);   // k ascending, single acc
                aL = fmaf(x1, wL.y, aL);
                aL = fmaf(x2, wL.z, aL);
                aL = fmaf(x3, wL.w, aL);
                aH = fmaf(x0, wH.x, aH);
                aH = fmaf(x1, wH.y, aH);
                aH = fmaf(x2, wH.z, aH);
                aH = fmaf(x3, wH.w, aH);
                accL[j] = aL; accH[j] = aH;
            }
        }
        __syncthreads();
    }

    const float bL = b1[lane], bH = b1[64 + lane];
    #pragma unroll
    for (int j = 0; j < 8; ++j) {
        const size_t rg = rowg0 + wv * 8 + j;
        ws[rg * HID + lane]      = accL[j] + bL;   // one rounded add each
        ws[rg * HID + 64 + lane] = accH[j] + bH;
    }
}

// ---------------- kernel B: temporal loop, 4-t batched, fp16-packed -------
#define B_RPB  32
#define B_THR  256
#define RSTR   260    // pk row stride (u32); =4 mod 32 -> staggered banks

// pack two {0.0f,1.0f} spikes into one u32 as fp16 pair (lo=a, hi=b).
// RTZ conversion of 0.0/1.0 is exact; 1 VALU inst replaces shift+or.
static __device__ __forceinline__ unsigned int pkspk(float a, float b) {
    auto h = __builtin_amdgcn_cvt_pkrtz(a, b);   // __fp16 ext_vector(2), 4B
    return __builtin_bit_cast(unsigned int, h);
}

__global__ __launch_bounds__(B_THR, 2)
void snn_tloop(const float* __restrict__ ws, const float* __restrict__ W2,
               const float* __restrict__ b2, float* __restrict__ out)
{
#pragma clang fp contract(off)
    __shared__ unsigned int pk[B_RPB * RSTR];   // 33.3 KB packed spikes
    __shared__ float4 w2l[NCLS * 32];           // 4 KB: [cls][g]

    const int tid = threadIdx.x;
    const int r   = tid >> 3;            // phase-a row 0..31
    const int q   = tid & 7;             // phase-a h-block

    w2l[tid] = ((const float4*)W2)[tid];

    float cur1[16];
    {
        const float* src = ws + ((size_t)blockIdx.x * B_RPB + r) * HID + q * 16;
        #pragma unroll
        for (int i = 0; i < 4; ++i) {
            const float4 v = *(const float4*)(src + 4 * i);
            cur1[4*i+0] = v.x; cur1[4*i+1] = v.y;
            cur1[4*i+2] = v.z; cur1[4*i+3] = v.w;
        }
    }

    const int lane = tid & 63;
    const int brow = lane & 31;
    const int bcls = 2 * (tid >> 6) + (lane >> 5);
    const float b2c = b2[bcls];
    const float4* __restrict__ w2p = &w2l[bcls * 32];

    float mem1[16], spk1[16];
    #pragma unroll
    for (int i = 0; i < 16; ++i) { mem1[i] = 0.0f; spk1[i] = 0.0f; }
    float m2 = 0.0f, r2v = 0.0f, o = 0.0f;

    #pragma unroll 1
    for (int ts = 0; ts < T_STEPS; ts += 4) {
        #pragma unroll
        for (int j = 0; j < 4; ++j) {
            #pragma unroll
            for (int i = 0; i < 16; ++i) {
                float tmp = 0.9f * mem1[i];   // rounded mul
                tmp = tmp + cur1[i];          // rounded add
                float m = tmp - spk1[i];      // rounded sub
                mem1[i] = m;
                spk1[i] = (m > 1.0f) ? 1.0f : 0.0f;
            }
            unsigned int* dst = &pk[r * RSTR + j * 64 + q * 8];
            #pragma unroll
            for (int s = 0; s < 2; ++s) {
                uint4 pv;
                pv.x = pkspk(spk1[8*s+0], spk1[8*s+1]);   // lo=even h, hi=odd h
                pv.y = pkspk(spk1[8*s+2], spk1[8*s+3]);
                pv.z = pkspk(spk1[8*s+4], spk1[8*s+5]);
                pv.w = pkspk(spk1[8*s+6], spk1[8*s+7]);
                *(uint4*)(dst + 4 * s) = pv;
            }
        }
        __syncthreads();

        float a0 = 0.0f, a1 = 0.0f, a2 = 0.0f, a3 = 0.0f;
        const unsigned int* src = &pk[brow * RSTR];
        // v_fma_mix_f32: src0 = fp16 half of packed word (exact 0/1 -> f32),
        // src1 = f32 W2, src2 = f32 acc; single f32 rounding — bit-identical
        // to fmaf(spk, w, acc), h-ascending. LO half = even h, HI = odd h.
#define FMIX_LO(A, P, W) \
        asm("v_fma_mix_f32 %0, %1, %2, %0 op_sel_hi:[1,0,0]" \
            : "+v"(A) : "v"(P), "v"(W));
#define FMIX_HI(A, P, W) \
        asm("v_fma_mix_f32 %0, %1, %2, %0 op_sel:[1,0,0] op_sel_hi:[1,0,0]" \
            : "+v"(A) : "v"(P), "v"(W));
#define TR(A, P) \
        FMIX_LO(A, P.x, wA.x) FMIX_HI(A, P.x, wA.y) \
        FMIX_LO(A, P.y, wA.z) FMIX_HI(A, P.y, wA.w) \
        FMIX_LO(A, P.z, wB.x) FMIX_HI(A, P.z, wB.y) \
        FMIX_LO(A, P.w, wB.z) FMIX_HI(A, P.w, wB.w)
        #pragma unroll
        for (int gg = 0; gg < 16; ++gg) {
            const float4 wA = w2p[2 * gg];
            const float4 wB = w2p[2 * gg + 1];
            const uint4 p0 = *(const uint4*)(src + 0 * 64 + 4 * gg);
            const uint4 p1 = *(const uint4*)(src + 1 * 64 + 4 * gg);
            const uint4 p2 = *(const uint4*)(src + 2 * 64 + 4 * gg);
            const uint4 p3 = *(const uint4*)(src + 3 * 64 + 4 * gg);
            TR(a0, p0) TR(a1, p1) TR(a2, p2) TR(a3, p3)
        }
#undef TR
#undef FMIX_HI
#undef FMIX_LO
        __syncthreads();

        const float aa[4] = {a0, a1, a2, a3};
        #pragma unroll
        for (int j = 0; j < 4; ++j) {
            const float c2 = aa[j] + b2c;
            float t2 = 0.9f * m2; t2 = t2 + c2; m2 = t2 - r2v;
            r2v = (m2 > 1.0f) ? 1.0f : 0.0f;
            o = o + r2v;
        }
    }

    out[((size_t)blockIdx.x * B_RPB + brow) * NCLS + bcls] = o;
}

extern "C" void kernel_launch(void* const* d_in, const int* in_sizes, int n_in,
                              void* d_out, int out_size, void* d_ws, size_t ws_size,
                              hipStream_t stream) {
    const float* x  = (const float*)d_in[0];
    const float* W1 = (const float*)d_in[1];
    const float* b1 = (const float*)d_in[2];
    const float* W2 = (const float*)d_in[3];
    const float* b2 = (const float*)d_in[4];
    float* out = (float*)d_out;
    float* cur_ws = (float*)d_ws;        // [BATCH x HID] = 8 MB

    const int batch = in_sizes[0] / IN_DIM;          // 16384
    snn_gemm<<<batch / A_ROWS, A_THR, 0, stream>>>(x, W1, b1, cur_ws);
    snn_tloop<<<batch / B_RPB, B_THR, 0, stream>>>(cur_ws, W2, b2, out);
}

// Round 3
// 144.981 us; speedup vs baseline: 1.1299x; 1.0280x over previous
//
#include <hip/hip_runtime.h>
#include <math.h>

// TemporalSNNClassifier — bit-exact fp32 emulation (absmax 0.0 since r2).
//
// r17: FUSED gemm+tloop. Both kernels were ~66us with ~15-17us of
// inter-kernel cost (device-wide sync at the kernel boundary + 8MB ws HBM
// round-trip + second launch). Rows/block (32) and threads (256) already
// match, so fuse structurally: gemm phase -> write cur1 tile to LDS ->
// tloop phase, internals VERBATIM. One 41.7KB LDS arena, time-multiplexed:
//   gemm:   w1c [16][130] float4 (33280B @0) + xcf 64*33 f32 (8448B @33280)
//   handoff wsl 32*128 f32 (16384B @0, aliases dead w1c)
//   tloop:  pk 32*260 u32 (33280B @0) + w2l 256 float4 (4096B @33280)
// Barriers at each aliasing transition. ws values bit-identical through
// LDS; every arithmetic sequence unchanged -> absmax 0.0 preserved.
//
// r16b evidence: fma_mix cut tloop 82->66us, VALUBusy 85->61% (LDS pipe
// co-limiting, as predicted). r15 evidence: unified law (r10+r12+m136):
// 16B-per-lane reads are NEVER deduplicated — wave-uniform b128 moves
// 64x16B serialized (~64cyc); b32 same-address broadcast is FREE (m136).
//
// FROZEN numerics: k-ascending single-accumulator fmaf chains (GEMM1),
// h-ascending 0..127 chain per (row,class,t) via v_fma_mix_f32 over fp16
// spike pairs (exact for {0,1}, single f32 rounding == fmaf(spk,w,acc)),
// bias as one separate add, leaky update ((0.9f*mem)+cur)-reset with
// contraction off, spike <=> mem > 1.0f, reset_t == spk_{t-1}.

#define T_STEPS 64
#define IN_DIM  256
#define HID     128
#define NCLS    8

#define ROWS   32     // rows per block (both phases)
#define THR    256
#define A_KQ   16     // float4 k-quads per chunk (64 k)
#define RSTR   260    // pk row stride (u32); =4 mod 32 -> staggered banks

// pack two {0.0f,1.0f} spikes into one u32 as fp16 pair (lo=a, hi=b).
static __device__ __forceinline__ unsigned int pkspk(float a, float b) {
    auto h = __builtin_amdgcn_cvt_pkrtz(a, b);   // __fp16 ext_vector(2), 4B
    return __builtin_bit_cast(unsigned int, h);
}

__global__ __launch_bounds__(THR, 2)
void snn_fused(const float* __restrict__ x, const float* __restrict__ W1,
               const float* __restrict__ b1, const float* __restrict__ W2,
               const float* __restrict__ b2, float* __restrict__ out)
{
#pragma clang fp contract(off)
    __shared__ __align__(16) char smem[41728];
    float4 (* const w1c)[HID + 2] = (float4 (*)[HID + 2])smem;   // [16][130]
    float*        const xcf = (float*)(smem + 33280);            // 64*33
    unsigned int* const pk  = (unsigned int*)smem;               // 32*260
    float4*       const w2l = (float4*)(smem + 33280);           // 256
    float*        const wsl = (float*)smem;                      // 32*128

    const int tid  = threadIdx.x;
    const int lane = tid & 63;

    // ================= phase 1: cur1 GEMM (r15 verbatim) =================
    {
        const int wv = __builtin_amdgcn_readfirstlane(tid >> 6);   // 0..3
        const size_t rowg0 = (size_t)blockIdx.x * ROWS;

        float accL[8], accH[8];
        #pragma unroll
        for (int j = 0; j < 8; ++j) { accL[j] = 0.0f; accH[j] = 0.0f; }

        #pragma unroll 1
        for (int ch = 0; ch < 4; ++ch) {
            const int kbase = ch * (A_KQ * 4);
            // stage W1 chunk: 2048 float4, 8 per thread (coalesced per h-row)
            #pragma unroll
            for (int s = 0; s < 8; ++s) {
                const int idx = tid + s * THR;
                const int h = idx >> 4, kq = idx & 15;
                w1c[kq][h] = *(const float4*)(W1 + (size_t)h * IN_DIM + kbase + kq * 4);
            }
            // stage x chunk c-major: quad (rr,kq) -> xcf[(4kq+c)*33 + rr]
            #pragma unroll
            for (int s = 0; s < 2; ++s) {
                const int idx = tid + s * THR;
                const int rr = idx >> 4, kq = idx & 15;
                const float4 v = *(const float4*)(x + (rowg0 + rr) * IN_DIM + kbase + kq * 4);
                xcf[(4 * kq + 0) * 33 + rr] = v.x;
                xcf[(4 * kq + 1) * 33 + rr] = v.y;
                xcf[(4 * kq + 2) * 33 + rr] = v.z;
                xcf[(4 * kq + 3) * 33 + rr] = v.w;
            }
            __syncthreads();

            #pragma unroll 4
            for (int kq = 0; kq < A_KQ; ++kq) {
                const float4 wL = w1c[kq][lane];        // lane-contig 1KB
                const float4 wH = w1c[kq][64 + lane];
                #pragma unroll
                for (int j = 0; j < 8; ++j) {
                    const int rb = wv * 8 + j;
                    // 4 separate b32 broadcasts (132B apart -> no b128 merge)
                    const float x0 = xcf[(4 * kq + 0) * 33 + rb];
                    const float x1 = xcf[(4 * kq + 1) * 33 + rb];
                    const float x2 = xcf[(4 * kq + 2) * 33 + rb];
                    const float x3 = xcf[(4 * kq + 3) * 33 + rb];
                    float aL = accL[j], aH = accH[j];
                    aL = fmaf(x0, wL.x, aL);   // k ascending, single acc
                    aL = fmaf(x1, wL.y, aL);
                    aL = fmaf(x2, wL.z, aL);
                    aL = fmaf(x3, wL.w, aL);
                    aH = fmaf(x0, wH.x, aH);
                    aH = fmaf(x1, wH.y, aH);
                    aH = fmaf(x2, wH.z, aH);
                    aH = fmaf(x3, wH.w, aH);
                    accL[j] = aL; accH[j] = aH;
                }
            }
            __syncthreads();   // also fences w1c/xcf before re-stage / alias
        }

        // handoff: cur1 tile -> LDS (aliases dead w1c). Values bit-identical
        // to the old global ws path (same accL/accH + one rounded bias add).
        const float bL = b1[lane], bH = b1[64 + lane];
        #pragma unroll
        for (int j = 0; j < 8; ++j) {
            const int rr = wv * 8 + j;
            wsl[rr * HID + lane]      = accL[j] + bL;
            wsl[rr * HID + 64 + lane] = accH[j] + bH;
        }
        // stage W2 (region aliases dead xcf, disjoint from wsl)
        w2l[tid] = ((const float4*)W2)[tid];
    }
    __syncthreads();

    // ================= phase 2: temporal loop (r16b verbatim) =============
    const int r = tid >> 3;            // phase-a row 0..31
    const int q = tid & 7;             // phase-a h-block

    float cur1[16];
    {
        const float* src = wsl + r * HID + q * 16;
        #pragma unroll
        for (int i = 0; i < 4; ++i) {
            const float4 v = *(const float4*)(src + 4 * i);
            cur1[4*i+0] = v.x; cur1[4*i+1] = v.y;
            cur1[4*i+2] = v.z; cur1[4*i+3] = v.w;
        }
    }
    __syncthreads();   // cur1 read complete before pk overwrites wsl region

    const int brow = lane & 31;
    const int bcls = 2 * (tid >> 6) + (lane >> 5);
    const float b2c = b2[bcls];
    const float4* __restrict__ w2p = &w2l[bcls * 32];

    float mem1[16], spk1[16];
    #pragma unroll
    for (int i = 0; i < 16; ++i) { mem1[i] = 0.0f; spk1[i] = 0.0f; }
    float m2 = 0.0f, r2v = 0.0f, o = 0.0f;

    #pragma unroll 1
    for (int ts = 0; ts < T_STEPS; ts += 4) {
        #pragma unroll
        for (int j = 0; j < 4; ++j) {
            #pragma unroll
            for (int i = 0; i < 16; ++i) {
                float tmp = 0.9f * mem1[i];   // rounded mul
                tmp = tmp + cur1[i];          // rounded add
                float m = tmp - spk1[i];      // rounded sub
                mem1[i] = m;
                spk1[i] = (m > 1.0f) ? 1.0f : 0.0f;
            }
            unsigned int* dst = &pk[r * RSTR + j * 64 + q * 8];
            #pragma unroll
            for (int s = 0; s < 2; ++s) {
                uint4 pv;
                pv.x = pkspk(spk1[8*s+0], spk1[8*s+1]);   // lo=even h, hi=odd h
                pv.y = pkspk(spk1[8*s+2], spk1[8*s+3]);
                pv.z = pkspk(spk1[8*s+4], spk1[8*s+5]);
                pv.w = pkspk(spk1[8*s+6], spk1[8*s+7]);
                *(uint4*)(dst + 4 * s) = pv;
            }
        }
        __syncthreads();

        float a0 = 0.0f, a1 = 0.0f, a2 = 0.0f, a3 = 0.0f;
        const unsigned int* src = &pk[brow * RSTR];
        // v_fma_mix_f32: src0 = fp16 half of packed word (exact 0/1 -> f32),
        // src1 = f32 W2, src2 = f32 acc; single f32 rounding — bit-identical
        // to fmaf(spk, w, acc), h-ascending. LO half = even h, HI = odd h.
#define FMIX_LO(A, P, W) \
        asm("v_fma_mix_f32 %0, %1, %2, %0 op_sel_hi:[1,0,0]" \
            : "+v"(A) : "v"(P), "v"(W));
#define FMIX_HI(A, P, W) \
        asm("v_fma_mix_f32 %0, %1, %2, %0 op_sel:[1,0,0] op_sel_hi:[1,0,0]" \
            : "+v"(A) : "v"(P), "v"(W));
#define TR(A, P) \
        FMIX_LO(A, P.x, wA.x) FMIX_HI(A, P.x, wA.y) \
        FMIX_LO(A, P.y, wA.z) FMIX_HI(A, P.y, wA.w) \
        FMIX_LO(A, P.z, wB.x) FMIX_HI(A, P.z, wB.y) \
        FMIX_LO(A, P.w, wB.z) FMIX_HI(A, P.w, wB.w)
        #pragma unroll
        for (int gg = 0; gg < 16; ++gg) {
            const float4 wA = w2p[2 * gg];
            const float4 wB = w2p[2 * gg + 1];
            const uint4 p0 = *(const uint4*)(src + 0 * 64 + 4 * gg);
            const uint4 p1 = *(const uint4*)(src + 1 * 64 + 4 * gg);
            const uint4 p2 = *(const uint4*)(src + 2 * 64 + 4 * gg);
            const uint4 p3 = *(const uint4*)(src + 3 * 64 + 4 * gg);
            TR(a0, p0) TR(a1, p1) TR(a2, p2) TR(a3, p3)
        }
#undef TR
#undef FMIX_HI
#undef FMIX_LO
        __syncthreads();

        const float aa[4] = {a0, a1, a2, a3};
        #pragma unroll
        for (int j = 0; j < 4; ++j) {
            const float c2 = aa[j] + b2c;
            float t2 = 0.9f * m2; t2 = t2 + c2; m2 = t2 - r2v;
            r2v = (m2 > 1.0f) ? 1.0f : 0.0f;
            o = o + r2v;
        }
    }

    out[((size_t)blockIdx.x * ROWS + brow) * NCLS + bcls] = o;
}

extern "C" void kernel_launch(void* const* d_in, const int* in_sizes, int n_in,
                              void* d_out, int out_size, void* d_ws, size_t ws_size,
                              hipStream_t stream) {
    const float* x  = (const float*)d_in[0];
    const float* W1 = (const float*)d_in[1];
    const float* b1 = (const float*)d_in[2];
    const float* W2 = (const float*)d_in[3];
    const float* b2 = (const float*)d_in[4];
    float* out = (float*)d_out;
    (void)d_ws; (void)ws_size;

    const int batch = in_sizes[0] / IN_DIM;          // 16384
    snn_fused<<<batch / ROWS, THR, 0, stream>>>(x, W1, b1, W2, b2, out);
}